// Round 7
// baseline (197.867 us; speedup 1.0000x reference)
//
#include <hip/hip_runtime.h>
#include <stdint.h>

#define BATCH 32
#define IMG 512
#define CH 3
#define GOUT 64
#define ROWB (IMG*CH)   // 1536 floats per image row

typedef __attribute__((ext_vector_type(8))) short  short8;   // 8 bf16 = 4 VGPRs
typedef __attribute__((ext_vector_type(4))) float  floatx4;  // MFMA 16x16 acc

__device__ __forceinline__ unsigned short f2bf(float x) {
    unsigned u = __builtin_bit_cast(unsigned, x);
    u += 0x7FFFu + ((u >> 16) & 1u);
    return (unsigned short)(u >> 16);
}

typedef __attribute__((address_space(3))) unsigned int  lds_u32;
typedef __attribute__((address_space(1))) const unsigned int g_u32;
__device__ __forceinline__ void async16(const void* g, void* l) {
    __builtin_amdgcn_global_load_lds((g_u32*)(uintptr_t)g,
                                     (lds_u32*)(uintptr_t)l, 16, 0, 0);
}

// ---------------------------------------------------------------------------
// Kernel 1: Gaussian filterbank masks, TRANSPOSED bf16: AyT[b][H][h],
// AxT[b][W][w] (k-contiguous). One wave per (b, axis, r).
// ---------------------------------------------------------------------------
__global__ __launch_bounds__(64) void mask_kernel(const float* __restrict__ tp,
                                                  unsigned short* __restrict__ AyT,
                                                  unsigned short* __restrict__ AxT) {
    int blk  = blockIdx.x;
    int r    = blk & 63;
    int axis = (blk >> 6) & 1;
    int b    = blk >> 7;

    const float* p = tp + b*6 + (axis ? 3 : 0);
    float u = p[0], s = p[1], d = p[2];
    float centre = u + (float)r * d;
    float inv_s  = 1.0f / s;

    int lane = threadIdx.x;
    float e[8];
    float sum = 0.0f;
    #pragma unroll
    for (int i = 0; i < 8; ++i) {
        float z = ((float)(i*64 + lane) - centre) * inv_s;
        e[i] = __expf(-0.5f * z * z);
        sum += e[i];
    }
    #pragma unroll
    for (int m = 1; m < 64; m <<= 1)
        sum += __shfl_xor(sum, m, 64);
    float inv_sum = 1.0f / (sum + 1e-8f);

    unsigned short* dst = (axis ? AxT : AyT) + ((size_t)b*GOUT + r) * IMG;
    #pragma unroll
    for (int i = 0; i < 8; ++i)
        dst[i*64 + lane] = f2bf(e[i] * inv_sum);
}

// ---------------------------------------------------------------------------
// Kernel 2: gB[b][c][H][w] (bf16) = sum_h Ay[b,h,H] * img[b,h,w,c]
// WAVE-SYNCHRONOUS pipelined MFMA — zero __syncthreads in the K-loop.
// (r6 lesson: the per-chunk barrier forces vmcnt(0) queue drains; with tiny
// per-chunk compute the kernel was all drain tail.)
// Each wave: 16 wc cols x 64 H x K=512, private LDS slab 2x2 KB dbuf.
// Per BK=32 chunk: prefetch next (4x b128 AyT->reg + 2x async16 img->LDS),
// s_waitcnt vmcnt(6) (AITER-style, never drains prefetch), 8 conflict-lite
// ds_read_b32 + cvt, 4 MFMA. Rows in LDS are k-PERMUTED (row(k)=4*(k&7)+(k>>3))
// so async's lane*16 dest constraint and read-side bank spread coexist
// (read banks: 16q%32 -> 2-way only = free, m136).
// 128-thr blocks, grid 32*48=1536 (6/CU), 8 KB LDS.
// ---------------------------------------------------------------------------
__global__ __launch_bounds__(128, 6) void stage1_kernel(const float* __restrict__ img,
                                                        const unsigned short* __restrict__ AyT,
                                                        unsigned short* __restrict__ gB) {
    __shared__ float Bs[2][2][512];   // [wave][buf][32 k-rows x 16 n]

    int tile = blockIdx.x % 48;
    int b    = blockIdx.x / 48;
    int tid  = threadIdx.x;
    int wave = tid >> 6;
    int lane = tid & 63;
    int n16  = lane & 15;
    int q    = lane >> 4;
    int wc0  = tile*32 + wave*16;

    const float*          imb = img + (size_t)b*IMG*ROWB + wc0;
    const unsigned short* ayb = AyT + ((size_t)b*GOUT + n16) * IMG;

    // async staging map: lane covers LDS slot lane*16B = k-row (lane>>2),
    // n-group (lane&3)*4; stored k = kb + 4t, kb = ((lane>>2)>>2) + 8*((lane>>2)&3)
    int l4 = lane >> 2;
    int c4 = (lane & 3) * 4;
    int kb = (l4 >> 2) + 8*(l4 & 3);

    floatx4 acc[4];
    #pragma unroll
    for (int mt = 0; mt < 4; ++mt) acc[mt] = (floatx4){0.f, 0.f, 0.f, 0.f};
    short8 af[2][4];

    // prologue: chunk 0
    #pragma unroll
    for (int mt = 0; mt < 4; ++mt)
        af[0][mt] = *(const short8*)(ayb + (size_t)mt*16*IMG + q*8);
    #pragma unroll
    for (int t = 0; t < 2; ++t)
        async16(imb + (size_t)(kb + 4*t)*ROWB + c4, &Bs[wave][0][t*256 + lane*4]);

    #pragma unroll
    for (int i = 0; i < 16; ++i) {
        int buf = i & 1;
        if (i < 15) {
            int h1 = (i+1)*32;
            #pragma unroll
            for (int mt = 0; mt < 4; ++mt)
                af[(i+1)&1][mt] = *(const short8*)(ayb + (size_t)mt*16*IMG + h1 + q*8);
            #pragma unroll
            for (int t = 0; t < 2; ++t)
                async16(imb + (size_t)(h1 + kb + 4*t)*ROWB + c4,
                        &Bs[wave][(i+1)&1][t*256 + lane*4]);
            asm volatile("s_waitcnt vmcnt(6)" ::: "memory");
        } else {
            asm volatile("s_waitcnt vmcnt(0)" ::: "memory");
        }
        // compute chunk i: bf[j] = img[k=q*8+j][wc0+n16] at LDS row 4j+q
        float tmp[8];
        #pragma unroll
        for (int j = 0; j < 8; ++j)
            tmp[j] = Bs[wave][buf][(4*j + q)*16 + n16];
        short8 bf;
        #pragma unroll
        for (int j = 0; j < 8; ++j)
            bf[j] = (short)f2bf(tmp[j]);
        #pragma unroll
        for (int mt = 0; mt < 4; ++mt)
            acc[mt] = __builtin_amdgcn_mfma_f32_16x16x32_bf16(af[buf][mt], bf, acc[mt], 0, 0, 0);
    }

    // Epilogue: D col = lane&15 -> wc, row = q*4+reg -> H (verified r4-r6).
    int wc = wc0 + n16;
    int c = wc % 3, w = wc / 3;
    unsigned short* gb = gB + ((size_t)(b*CH + c) * GOUT) * IMG + w;
    #pragma unroll
    for (int mt = 0; mt < 4; ++mt)
        #pragma unroll
        for (int reg = 0; reg < 4; ++reg)
            gb[(size_t)(mt*16 + q*4 + reg) * IMG] = f2bf(acc[mt][reg]);
}

// ---------------------------------------------------------------------------
// Kernel 3: out[b,H,W,c] += sum_{w part} gB[b,c,H,w] * Ax[b,w,W]
// bf16 MFMA; grid (b,c,part)=384; K-split 4, fp32 atomicAdd into zeroed out.
// gB is now bf16 -> A-frag is a single b128 load, no conversions.
// ---------------------------------------------------------------------------
__global__ __launch_bounds__(256) void stage2_kernel(const unsigned short* __restrict__ gB,
                                                     const unsigned short* __restrict__ AxT,
                                                     float* __restrict__ out) {
    int blk  = blockIdx.x;
    int part = blk & 3;
    int bc   = blk >> 2;
    int c    = bc % 3;
    int b    = bc / 3;
    int tid  = threadIdx.x;
    int wm   = tid >> 6;
    int lane = tid & 63;
    int n16  = lane & 15;
    int q    = lane >> 4;

    floatx4 acc[4];
    #pragma unroll
    for (int nt = 0; nt < 4; ++nt) acc[nt] = (floatx4){0.f, 0.f, 0.f, 0.f};

    const unsigned short* ga  = gB  + ((size_t)(b*CH + c) * GOUT + wm*16 + n16) * IMG;
    const unsigned short* axb = AxT + ((size_t)b*GOUT + n16) * IMG;

    #pragma unroll
    for (int cc = 0; cc < 4; ++cc) {
        int w0 = part*128 + cc*32;
        short8 af = *(const short8*)(ga + w0 + q*8);
        #pragma unroll
        for (int nt = 0; nt < 4; ++nt) {
            short8 bf = *(const short8*)(axb + (size_t)nt*16*IMG + w0 + q*8);
            acc[nt] = __builtin_amdgcn_mfma_f32_16x16x32_bf16(af, bf, acc[nt], 0, 0, 0);
        }
    }

    #pragma unroll
    for (int nt = 0; nt < 4; ++nt) {
        int W = nt*16 + n16;
        #pragma unroll
        for (int reg = 0; reg < 4; ++reg) {
            int H = wm*16 + q*4 + reg;
            atomicAdd(out + (((size_t)b*GOUT + H) * GOUT + W) * CH + c, acc[nt][reg]);
        }
    }
}

// ---------------------------------------------------------------------------
// Workspace: AyT 2 MB | AxT 2 MB | gB 12.6 MB bf16.
// ---------------------------------------------------------------------------
extern "C" void kernel_launch(void* const* d_in, const int* in_sizes, int n_in,
                              void* d_out, int out_size, void* d_ws, size_t ws_size,
                              hipStream_t stream) {
    const float* img = (const float*)d_in[0];
    const float* tp  = (const float*)d_in[1];
    float* out = (float*)d_out;

    unsigned short* AyT = (unsigned short*)d_ws;
    unsigned short* AxT = AyT + (size_t)BATCH * GOUT * IMG;
    unsigned short* gB  = AxT + (size_t)BATCH * GOUT * IMG;

    hipMemsetAsync(d_out, 0, (size_t)out_size * sizeof(float), stream);
    mask_kernel  <<<BATCH * 2 * GOUT,  64, 0, stream>>>(tp, AyT, AxT);
    stage1_kernel<<<BATCH * 48,       128, 0, stream>>>(img, AyT, gB);
    stage2_kernel<<<BATCH * CH * 4,   256, 0, stream>>>(gB, AxT, out);
}